// Round 6
// baseline (766.721 us; speedup 1.0000x reference)
//
#include <hip/hip_runtime.h>

// FM-CTR forward — R7 DIAGNOSTIC BUILD.
// Identical memory structure to R6 (best: 735.6us), but the grid is
// DOUBLED and b masked so every sample is computed twice (two waves write
// identical out[b] values -> result unchanged). Purpose: the kernel
// dispatch becomes ~2x the harness's 415us fill dispatches and therefore
// finally appears in the top-5 rocprof rows with its full counter set
// (FETCH_SIZE / OccupancyPercent / VALUBusy / hbm_gbps), all at exactly
// 2x the true kernel values. Discriminates over-fetch vs request-rate cap
// vs latency-bound. Revert = set GRID_MULT back to 1.

constexpr int N_TABLES  = 26;
constexpr int VOCAB     = 50000;
constexpr int EMBED_DIM = 128;
constexpr int DENSE_DIM = 13;
constexpr int BATCH     = 16384;
constexpr int CHUNK     = 13;   // gathers staged per chunk (26 VGPRs)
constexpr int GRID_MULT = 2;    // DIAGNOSTIC: 2x redundant work

typedef float f32x2 __attribute__((ext_vector_type(2)));

__global__ __launch_bounds__(256, 8) void fmctr_kernel(
    const float* __restrict__ dense_x,     // (BATCH, 13)
    const int*   __restrict__ discrete_x,  // (BATCH, 26) int32
    const float* __restrict__ emb,         // (26, 50000, 128)
    const float* __restrict__ dense_w,     // (128, 13)
    const float* __restrict__ dense_b,     // (128,)
    float*       __restrict__ out)         // (BATCH,)
{
    // one wave per (redundant) sample slot; mask to real sample id
    const int b    = __builtin_amdgcn_readfirstlane(
                         ((blockIdx.x * 256 + threadIdx.x) >> 6) & (BATCH - 1));
    const int lane = threadIdx.x & 63;     // 64 lanes x 2 dims

    // ---- fetch 26 indices + 13 dense features in TWO coalesced requests ----
    int   myidx = 0;
    float myx   = 0.f;
    if (lane < N_TABLES)  myidx = discrete_x[(long)b * N_TABLES + lane];
    if (lane < DENSE_DIM) myx   = dense_x[(long)b * DENSE_DIM + lane];

    // broadcast indices into SGPRs (readlane with literal lane index)
    int idx[N_TABLES];
#pragma unroll
    for (int t = 0; t < N_TABLES; ++t)
        idx[t] = __builtin_amdgcn_readlane(myidx, t);

    // broadcast dense features into SGPRs
    float xv[DENSE_DIM];
#pragma unroll
    for (int k = 0; k < DENSE_DIM; ++k)
        xv[k] = __builtin_bit_cast(float,
                    __builtin_amdgcn_readlane(__builtin_bit_cast(int, myx), k));

    // ---- gather: 2 chunks of 13 non-temporal 8B loads, saddr form ----
    const char* embB = (const char*)emb;
    const unsigned loff = (unsigned)lane * 8u;   // the ONLY vector offset
    float s0 = 0.f, s1 = 0.f, q0 = 0.f, q1 = 0.f;

#pragma unroll
    for (int c = 0; c < N_TABLES; c += CHUNK) {
        f32x2 v[CHUNK];
#pragma unroll
        for (int j = 0; j < CHUNK; ++j) {
            const int t = c + j;
            const unsigned off =
                (unsigned)(t * VOCAB + idx[t]) * (unsigned)(EMBED_DIM * 4);
            v[j] = __builtin_nontemporal_load(
                       (const f32x2*)(embB + off + loff));
        }
#pragma unroll
        for (int j = 0; j < CHUNK; ++j) {
            s0 += v[j].x;          s1 += v[j].y;
            q0 += v[j].x * v[j].x; q1 += v[j].y * v[j].y;
        }
    }

    // ---- dense embedding for dims j0 = lane*2, j0+1 (tiny inline GEMV) ----
    const int j0 = lane * 2;
    const float* w0 = dense_w + (long)j0 * DENSE_DIM;   // row j0, then row j0+1
    float d0 = dense_b[j0], d1 = dense_b[j0 + 1];
#pragma unroll
    for (int k = 0; k < DENSE_DIM; ++k) {
        d0 += xv[k] * w0[k];
        d1 += xv[k] * w0[DENSE_DIM + k];
    }

    float fm = 0.f;
    {
        const float ss0 = s0 + d0, qq0 = q0 + d0 * d0;
        fm += 0.5f * (ss0 * ss0 - qq0);
        const float ss1 = s1 + d1, qq1 = q1 + d1 * d1;
        fm += 0.5f * (ss1 * ss1 - qq1);
    }

    // ---- reduce fm across the 64 lanes of the wave ----
#pragma unroll
    for (int m = 32; m >= 1; m >>= 1)
        fm += __shfl_xor(fm, m, 64);

    // two waves write the identical value to out[b] -> benign
    if (lane == 0) out[b] = fm;
}

extern "C" void kernel_launch(void* const* d_in, const int* in_sizes, int n_in,
                              void* d_out, int out_size, void* d_ws, size_t ws_size,
                              hipStream_t stream) {
    const float* dense_x    = (const float*)d_in[0];
    const int*   discrete_x = (const int*)  d_in[1];
    const float* emb        = (const float*)d_in[2];
    const float* dense_w    = (const float*)d_in[3];
    const float* dense_b    = (const float*)d_in[4];
    float*       out        = (float*)d_out;

    // 256 threads = 4 waves = 4 sample-slots per block; GRID_MULT-fold work
    const int blocks = (BATCH * 64 * GRID_MULT) / 256;   // 8192
    fmctr_kernel<<<blocks, 256, 0, stream>>>(dense_x, discrete_x, emb,
                                             dense_w, dense_b, out);
}